// Round 7
// baseline (330.635 us; speedup 1.0000x reference)
//
#include <hip/hip_runtime.h>
#include <hip/hip_bf16.h>

// DenseEnergyLoss on MI355X. N=4, K=21, H=W=128 -> OH=OW=64, P=4096.
// loss = 0.1*(-0.5)/(N*P) * sum_{n,p,q} exp(-0.5*max(|f_p-f_q|^2,0)) * gate_p * <seg_p, seg_q>
// Symmetrized: gate_p -> (gate_p+gate_q)/2; upper-triangular 128x128 tile-pairs,
// diag tiles weighted 0.5 (off-diag x2 folded).
// R7: kill in-loop load latency. All b-fragments + q-scalars preloaded into
// registers before the compute loop (R6 paid ~200cyc L2 latency x8 iters).
// Combined 32-ch f16 row: ch0..20 seg_m, ch24..28 features, rest 0.
//   C1 = acomb x bcomb = G + fp.fq ; G = aseg0 x bcomb (aseg0 = acomb with
//   quad-3 lanes zeroed -> feat channels dead on A side) ; dot = C1 - G.
// MFMA layouts (HW-verified m89/m120): A/B point=lane&15, k=(lane>>4)*8+j;
// C/D col=lane&15, row=(lane>>4)*4+reg.

constexpr int N_ = 4, K_ = 21, H_ = 128, W_ = 128, P_ = 4096;
constexpr int T_ = 128;                  // tile size (p and q)
constexpr int NT = P_ / T_;              // 32 tiles per dim
constexpr int NTRI = NT * (NT + 1) / 2;  // 528 upper-tri tile pairs per n
constexpr int NBLK = NTRI * N_;          // 2112 energy blocks
constexpr float INV_RGB = 1.0f / 15.0f;
constexpr float INV_XY = 1.0f / 40.0f;   // 1/(SIGMA_XY*SCALE)
constexpr float LOG2E = 1.4426950408889634f;
constexpr float NEG_HALF_LOG2E = -0.72134752044448170f;
constexpr float OUT_SCALE = -0.05f / 16384.0f; // 0.1 * -0.5 / (N*P)

typedef _Float16 half8 __attribute__((ext_vector_type(8)));
typedef float floatx4 __attribute__((ext_vector_type(4)));

// Workspace: comb (N*P*32 f16 = 1 MB), scal (N*P float2), partial (NBLK f32).

__global__ void __launch_bounds__(256) prep_kernel(
    const float* __restrict__ img, const float* __restrict__ seg,
    const float* __restrict__ roi, const float* __restrict__ lab,
    _Float16* __restrict__ comb, float2* __restrict__ scal) {
  int idx = blockIdx.x * 256 + threadIdx.x; // n*P + p
  int n = idx >> 12;
  int p = idx & (P_ - 1);
  int y = p >> 6, x = p & 63;
  int iy = 2 * y, ix = 2 * x;
  const size_t hw = (size_t)H_ * W_;

  float r = roi[(size_t)n * hw + iy * W_ + ix];
  float lb = lab[(size_t)n * hw + iy * W_ + ix];
  bool unlabeled = ((int)lb == 255);

  const float* sb = seg + (size_t)n * K_ * hw + (size_t)iy * W_ + ix;
  _Float16 ch[32];
  float mx = -1e30f;
#pragma unroll
  for (int k = 0; k < K_; k++) {
    const float* s = sb + (size_t)k * hw;
    float v = 0.25f * (s[0] + s[1] + s[W_] + s[W_ + 1]); // bilinear @0.5 == 2x2 avg
    mx = fmaxf(mx, v);
    ch[k] = (_Float16)(v * r); // seg_m = seg_s * roi, rounded to f16
  }
  ch[21] = (_Float16)0.0f; ch[22] = (_Float16)0.0f; ch[23] = (_Float16)0.0f;

  const float* ib = img + (size_t)n * 3 * hw + (size_t)iy * W_ + ix;
  ch[24] = (_Float16)((float)x * INV_XY);
  ch[25] = (_Float16)((float)y * INV_XY);
  ch[26] = (_Float16)(ib[0] * INV_RGB);
  ch[27] = (_Float16)(ib[hw] * INV_RGB);
  ch[28] = (_Float16)(ib[2 * hw] * INV_RGB);
  ch[29] = (_Float16)0.0f; ch[30] = (_Float16)0.0f; ch[31] = (_Float16)0.0f;

  // cs from the ROUNDED features so diagonal d2 ~ 0 exactly.
  float sq = 0.0f;
#pragma unroll
  for (int j = 24; j < 29; j++) { float v = (float)ch[j]; sq = fmaf(v, v, sq); }

  float4* dst = (float4*)(comb + (size_t)idx * 32);
  const float4* src = (const float4*)ch;
#pragma unroll
  for (int j = 0; j < 4; j++) dst[j] = src[j];

  float g = unlabeled ? 1.0f : (r - mx);
  scal[idx] = make_float2(NEG_HALF_LOG2E * sq, fmaxf(g, 0.0f));
}

__global__ void __launch_bounds__(256) energy_kernel(
    const _Float16* __restrict__ comb, const float2* __restrict__ scal,
    float* __restrict__ partial) {
  // Decode upper-triangular tile pair (pb <= qb) from blockIdx.x in [0, 528).
  int t = blockIdx.x;
  int pb = 0;
  while (t >= NT - pb) { t -= NT - pb; pb++; }
  int qb = pb + t;
  int n = blockIdx.y;
  int tid = threadIdx.x;
  int lane = tid & 63, wave = tid >> 6;
  int m = lane & 15, quad = lane >> 4;

  const _Float16* combn = comb + (size_t)n * P_ * 32;
  const float2* scaln = scal + (size_t)n * P_;
  const half8 zfrag = {};

  // ---- Preload EVERYTHING into registers (no memory ops in compute loop) ----
  // A-side: 2 p-strips per wave.
  half8 acomb[2], aseg0[2];
#pragma unroll
  for (int s = 0; s < 2; s++) {
    int prow = pb * T_ + (2 * wave + s) * 16 + m;
    acomb[s] = *(const half8*)(combn + (size_t)prow * 32 + quad * 8);
    aseg0[s] = (quad == 3) ? zfrag : acomb[s]; // kill feat channels for G
  }
  // B-side: all 8 q-strips.
  half8 bcomb[8];
#pragma unroll
  for (int qs = 0; qs < 8; qs++) {
    int qrow = qb * T_ + qs * 16 + m;
    bcomb[qs] = *(const half8*)(combn + (size_t)qrow * 32 + quad * 8);
  }
  // q-side per-column scalars {csq, gq} for this lane's column m.
  float2 qsc[8];
#pragma unroll
  for (int qs = 0; qs < 8; qs++) qsc[qs] = scaln[qb * T_ + qs * 16 + m];
  // p-side per-row scalars for the 4 accumulator rows of each strip.
  float cspv[2][4], gpv[2][4];
#pragma unroll
  for (int s = 0; s < 2; s++)
#pragma unroll
    for (int r = 0; r < 4; r++) {
      float2 tpr = scaln[pb * T_ + (2 * wave + s) * 16 + quad * 4 + r];
      cspv[s][r] = tpr.x; gpv[s][r] = tpr.y;
    }

  // ---- Pure compute loop: 2 MFMA + ~26 VALU per (qs,s), no memory ----
  float acc = 0.0f;
#pragma unroll 2
  for (int qs = 0; qs < 8; qs++) {
#pragma unroll
    for (int s = 0; s < 2; s++) {
      floatx4 C1 = {0.0f, 0.0f, 0.0f, 0.0f};
      floatx4 G = {0.0f, 0.0f, 0.0f, 0.0f};
      C1 = __builtin_amdgcn_mfma_f32_16x16x32_f16(acomb[s], bcomb[qs], C1, 0, 0, 0);
      G = __builtin_amdgcn_mfma_f32_16x16x32_f16(aseg0[s], bcomb[qs], G, 0, 0, 0);
#pragma unroll
      for (int r = 0; r < 4; r++) {
        float dot = C1[r] - G[r];
        float arg = fmaf(LOG2E, dot, cspv[s][r] + qsc[qs].x);
        float A = __builtin_amdgcn_exp2f(arg);
        A = fminf(A, 1.0f);
        acc = fmaf(A * G[r], gpv[s][r] + qsc[qs].y, acc);
      }
    }
  }

  // Reduce within block; store partial to a distinct address (no atomics).
#pragma unroll
  for (int off = 32; off > 0; off >>= 1) acc += __shfl_down(acc, off, 64);
  __shared__ float wsum[4];
  if (lane == 0) wsum[wave] = acc;
  __syncthreads();
  if (tid == 0) {
    float s = (wsum[0] + wsum[1]) + (wsum[2] + wsum[3]);
    float wb = (pb == qb) ? 0.5f : 1.0f;
    partial[blockIdx.y * NTRI + blockIdx.x] = s * wb;
  }
}

__global__ void __launch_bounds__(256) reduce_kernel(
    const float* __restrict__ partial, float* __restrict__ out) {
  int tid = threadIdx.x;
  float acc = 0.0f;
  for (int i = tid; i < NBLK; i += 256) acc += partial[i];
#pragma unroll
  for (int off = 32; off > 0; off >>= 1) acc += __shfl_down(acc, off, 64);
  __shared__ float wsum[4];
  int lane = tid & 63, wave = tid >> 6;
  if (lane == 0) wsum[wave] = acc;
  __syncthreads();
  if (tid == 0) {
    float s = (wsum[0] + wsum[1]) + (wsum[2] + wsum[3]);
    out[0] = s * OUT_SCALE;
  }
}

extern "C" void kernel_launch(void* const* d_in, const int* in_sizes, int n_in,
                              void* d_out, int out_size, void* d_ws, size_t ws_size,
                              hipStream_t stream) {
  const float* images = (const float*)d_in[0];
  const float* segs = (const float*)d_in[1];
  const float* rois = (const float*)d_in[2];
  const float* labels = (const float*)d_in[3];
  float* out = (float*)d_out;

  char* ws = (char*)d_ws;
  _Float16* comb = (_Float16*)ws;                                  // 1 MB
  float2* scal = (float2*)(ws + (size_t)N_ * P_ * 32 * 2);         // 128 KB
  float* partial = (float*)(ws + (size_t)N_ * P_ * 32 * 2 +
                            (size_t)N_ * P_ * sizeof(float2));     // 8.25 KB

  prep_kernel<<<dim3(N_ * P_ / 256), dim3(256), 0, stream>>>(
      images, segs, rois, labels, comb, scal);
  energy_kernel<<<dim3(NTRI, N_), dim3(256), 0, stream>>>(comb, scal, partial);
  reduce_kernel<<<dim3(1), dim3(256), 0, stream>>>(partial, out);
}

// Round 8
// 81.870 us; speedup vs baseline: 4.0385x; 4.0385x over previous
//
#include <hip/hip_runtime.h>
#include <hip/hip_bf16.h>

// DenseEnergyLoss on MI355X. N=4, K=21, H=W=128 -> OH=OW=64, P=4096.
// loss = 0.1*(-0.5)/(N*P) * sum_{n,p,q} exp(-0.5*max(|f_p-f_q|^2,0)) * gate_p * <seg_p, seg_q>
// Symmetrized: gate_p -> (gate_p+gate_q)/2; upper-triangular 128x128 tile-pairs,
// diag tiles weighted 0.5 (off-diag x2 folded).
// R8: R7's preload-everything plan, but with the qs loop FULLY unrolled.
// R7's "#pragma unroll 2" left qs dynamic -> bcomb[qs]/qsc[qs] were demoted to
// LDS by PromoteAlloca (LDS_Block_Size 16896, 1.2M bank-conflict cycles, 278us).
// Full unroll keeps all fragments in VGPRs; compute loop has zero memory ops.
// Combined 32-ch f16 row: ch0..20 seg_m, ch24..28 features, rest 0.
//   C1 = acomb x bcomb = G + fp.fq ; G = aseg0 x bcomb (quad-3 A-lanes zeroed)
//   dot = C1 - G.
// MFMA layouts (HW-verified m89/m120): A/B point=lane&15, k=(lane>>4)*8+j;
// C/D col=lane&15, row=(lane>>4)*4+reg.

constexpr int N_ = 4, K_ = 21, H_ = 128, W_ = 128, P_ = 4096;
constexpr int T_ = 128;                  // tile size (p and q)
constexpr int NT = P_ / T_;              // 32 tiles per dim
constexpr int NTRI = NT * (NT + 1) / 2;  // 528 upper-tri tile pairs per n
constexpr int NBLK = NTRI * N_;          // 2112 energy blocks
constexpr float INV_RGB = 1.0f / 15.0f;
constexpr float INV_XY = 1.0f / 40.0f;   // 1/(SIGMA_XY*SCALE)
constexpr float LOG2E = 1.4426950408889634f;
constexpr float NEG_HALF_LOG2E = -0.72134752044448170f;
constexpr float OUT_SCALE = -0.05f / 16384.0f; // 0.1 * -0.5 / (N*P)

typedef _Float16 half8 __attribute__((ext_vector_type(8)));
typedef float floatx4 __attribute__((ext_vector_type(4)));

// Workspace: comb (N*P*32 f16 = 1 MB), scal (N*P float2), partial (NBLK f32).

__global__ void __launch_bounds__(256) prep_kernel(
    const float* __restrict__ img, const float* __restrict__ seg,
    const float* __restrict__ roi, const float* __restrict__ lab,
    _Float16* __restrict__ comb, float2* __restrict__ scal) {
  int idx = blockIdx.x * 256 + threadIdx.x; // n*P + p
  int n = idx >> 12;
  int p = idx & (P_ - 1);
  int y = p >> 6, x = p & 63;
  int iy = 2 * y, ix = 2 * x;
  const size_t hw = (size_t)H_ * W_;

  float r = roi[(size_t)n * hw + iy * W_ + ix];
  float lb = lab[(size_t)n * hw + iy * W_ + ix];
  bool unlabeled = ((int)lb == 255);

  const float* sb = seg + (size_t)n * K_ * hw + (size_t)iy * W_ + ix;
  _Float16 ch[32];
  float mx = -1e30f;
#pragma unroll
  for (int k = 0; k < K_; k++) {
    const float* s = sb + (size_t)k * hw;
    float v = 0.25f * (s[0] + s[1] + s[W_] + s[W_ + 1]); // bilinear @0.5 == 2x2 avg
    mx = fmaxf(mx, v);
    ch[k] = (_Float16)(v * r); // seg_m = seg_s * roi, rounded to f16
  }
  ch[21] = (_Float16)0.0f; ch[22] = (_Float16)0.0f; ch[23] = (_Float16)0.0f;

  const float* ib = img + (size_t)n * 3 * hw + (size_t)iy * W_ + ix;
  ch[24] = (_Float16)((float)x * INV_XY);
  ch[25] = (_Float16)((float)y * INV_XY);
  ch[26] = (_Float16)(ib[0] * INV_RGB);
  ch[27] = (_Float16)(ib[hw] * INV_RGB);
  ch[28] = (_Float16)(ib[2 * hw] * INV_RGB);
  ch[29] = (_Float16)0.0f; ch[30] = (_Float16)0.0f; ch[31] = (_Float16)0.0f;

  // cs from the ROUNDED features so diagonal d2 ~ 0 exactly.
  float sq = 0.0f;
#pragma unroll
  for (int j = 24; j < 29; j++) { float v = (float)ch[j]; sq = fmaf(v, v, sq); }

  float4* dst = (float4*)(comb + (size_t)idx * 32);
  const float4* src = (const float4*)ch;
#pragma unroll
  for (int j = 0; j < 4; j++) dst[j] = src[j];

  float g = unlabeled ? 1.0f : (r - mx);
  scal[idx] = make_float2(NEG_HALF_LOG2E * sq, fmaxf(g, 0.0f));
}

__global__ void __launch_bounds__(256) energy_kernel(
    const _Float16* __restrict__ comb, const float2* __restrict__ scal,
    float* __restrict__ partial) {
  // Decode upper-triangular tile pair (pb <= qb) from blockIdx.x in [0, 528).
  int t = blockIdx.x;
  int pb = 0;
  while (t >= NT - pb) { t -= NT - pb; pb++; }
  int qb = pb + t;
  int n = blockIdx.y;
  int tid = threadIdx.x;
  int lane = tid & 63, wave = tid >> 6;
  int m = lane & 15, quad = lane >> 4;

  const _Float16* combn = comb + (size_t)n * P_ * 32;
  const float2* scaln = scal + (size_t)n * P_;
  const half8 zfrag = {};

  // ---- Preload EVERYTHING into registers (no memory ops in compute loop) ----
  half8 acomb[2], aseg0[2];
#pragma unroll
  for (int s = 0; s < 2; s++) {
    int prow = pb * T_ + (2 * wave + s) * 16 + m;
    acomb[s] = *(const half8*)(combn + (size_t)prow * 32 + quad * 8);
    aseg0[s] = (quad == 3) ? zfrag : acomb[s]; // kill feat channels for G
  }
  half8 bcomb[8];
  float2 qsc[8];
#pragma unroll
  for (int qs = 0; qs < 8; qs++) {
    int qrow = qb * T_ + qs * 16 + m;
    bcomb[qs] = *(const half8*)(combn + (size_t)qrow * 32 + quad * 8);
    qsc[qs] = scaln[qb * T_ + qs * 16 + m];
  }
  float cspv[2][4], gpv[2][4];
#pragma unroll
  for (int s = 0; s < 2; s++)
#pragma unroll
    for (int r = 0; r < 4; r++) {
      float2 tpr = scaln[pb * T_ + (2 * wave + s) * 16 + quad * 4 + r];
      cspv[s][r] = tpr.x; gpv[s][r] = tpr.y;
    }

  // ---- Pure compute loop, FULLY unrolled: all indices compile-time ----
  float acc = 0.0f;
#pragma unroll
  for (int qs = 0; qs < 8; qs++) {
#pragma unroll
    for (int s = 0; s < 2; s++) {
      floatx4 C1 = {0.0f, 0.0f, 0.0f, 0.0f};
      floatx4 G = {0.0f, 0.0f, 0.0f, 0.0f};
      C1 = __builtin_amdgcn_mfma_f32_16x16x32_f16(acomb[s], bcomb[qs], C1, 0, 0, 0);
      G = __builtin_amdgcn_mfma_f32_16x16x32_f16(aseg0[s], bcomb[qs], G, 0, 0, 0);
#pragma unroll
      for (int r = 0; r < 4; r++) {
        float dot = C1[r] - G[r];
        float arg = fmaf(LOG2E, dot, cspv[s][r] + qsc[qs].x);
        float A = __builtin_amdgcn_exp2f(arg);
        A = fminf(A, 1.0f);
        acc = fmaf(A * G[r], gpv[s][r] + qsc[qs].y, acc);
      }
    }
  }

  // Reduce within block; store partial to a distinct address (no atomics).
#pragma unroll
  for (int off = 32; off > 0; off >>= 1) acc += __shfl_down(acc, off, 64);
  __shared__ float wsum[4];
  if (lane == 0) wsum[wave] = acc;
  __syncthreads();
  if (tid == 0) {
    float s = (wsum[0] + wsum[1]) + (wsum[2] + wsum[3]);
    float wb = (pb == qb) ? 0.5f : 1.0f;
    partial[blockIdx.y * NTRI + blockIdx.x] = s * wb;
  }
}

__global__ void __launch_bounds__(256) reduce_kernel(
    const float* __restrict__ partial, float* __restrict__ out) {
  int tid = threadIdx.x;
  float acc = 0.0f;
  for (int i = tid; i < NBLK; i += 256) acc += partial[i];
#pragma unroll
  for (int off = 32; off > 0; off >>= 1) acc += __shfl_down(acc, off, 64);
  __shared__ float wsum[4];
  int lane = tid & 63, wave = tid >> 6;
  if (lane == 0) wsum[wave] = acc;
  __syncthreads();
  if (tid == 0) {
    float s = (wsum[0] + wsum[1]) + (wsum[2] + wsum[3]);
    out[0] = s * OUT_SCALE;
  }
}

extern "C" void kernel_launch(void* const* d_in, const int* in_sizes, int n_in,
                              void* d_out, int out_size, void* d_ws, size_t ws_size,
                              hipStream_t stream) {
  const float* images = (const float*)d_in[0];
  const float* segs = (const float*)d_in[1];
  const float* rois = (const float*)d_in[2];
  const float* labels = (const float*)d_in[3];
  float* out = (float*)d_out;

  char* ws = (char*)d_ws;
  _Float16* comb = (_Float16*)ws;                                  // 1 MB
  float2* scal = (float2*)(ws + (size_t)N_ * P_ * 32 * 2);         // 128 KB
  float* partial = (float*)(ws + (size_t)N_ * P_ * 32 * 2 +
                            (size_t)N_ * P_ * sizeof(float2));     // 8.25 KB

  prep_kernel<<<dim3(N_ * P_ / 256), dim3(256), 0, stream>>>(
      images, segs, rois, labels, comb, scal);
  energy_kernel<<<dim3(NTRI, N_), dim3(256), 0, stream>>>(comb, scal, partial);
  reduce_kernel<<<dim3(1), dim3(256), 0, stream>>>(partial, out);
}